// Round 1
// baseline (534.002 us; speedup 1.0000x reference)
//
#include <hip/hip_runtime.h>
#include <stdint.h>

#define Bb 64
#define Hh 128
#define Ww 128
#define Cc 21
#define Pp 49152          // NUM_SAMPLED
#define Kk 36864          // NUM_UNCERTAIN
#define NR 12288          // NUM_RANDOM
#define WAVES 16

// ---------------------------------------------------------------------------
// Kernel 1: bilinear-sample channel 0, build sortable key.
// key = float bits of |interp| (non-negative fp32 bits are order-isomorphic
// to the value). Ascending |v| == descending uncertainty (-|v|).
// Packed element: (key << 16) | point_index   (idx < 49152 < 2^16).
// fp contract OFF so the arithmetic is bit-identical to numpy's
// p1*(1-mux)+p2*mux sequence — required because the sort permutation feeds
// straight into the output and any rank flip is an O(1) error.
// ---------------------------------------------------------------------------
__global__ void sample_key_kernel(const float* __restrict__ logits,
                                  const float2* __restrict__ coords,
                                  uint64_t* __restrict__ keys) {
#pragma clang fp contract(off)
    int gid = blockIdx.x * blockDim.x + threadIdx.x;   // gid in [0, B*P)
    int b = gid / Pp;
    int p = gid - b * Pp;
    float2 c = coords[gid];
    float xf = c.x * 127.0f;        // coords[...,0] indexes H axis, scale H-1
    float yf = c.y * 127.0f;        // coords[...,1] indexes W axis, scale W-1
    float x0 = floorf(xf), x1 = ceilf(xf);
    float y0 = floorf(yf), y1 = ceilf(yf);
    float mux = xf - x0;
    float muy = yf - y0;
    int x0i = (int)x0, x1i = (int)x1, y0i = (int)y0, y1i = (int)y1;
    const float* Lb = logits + (size_t)b * (Hh * Ww * Cc);
    float p1 = Lb[(x0i * Ww + y0i) * Cc];   // channel CLS=0 only
    float p2 = Lb[(x1i * Ww + y0i) * Cc];
    float p3 = Lb[(x0i * Ww + y1i) * Cc];
    float p4 = Lb[(x1i * Ww + y1i) * Cc];
    float p12 = p1 * (1.0f - mux) + p2 * mux;
    float p34 = p3 * (1.0f - mux) + p4 * mux;
    float r   = p12 * (1.0f - muy) + p34 * muy;
    uint32_t kb = __float_as_uint(r) & 0x7fffffffu;    // |r| bits
    keys[gid] = ((uint64_t)kb << 16) | (uint32_t)p;
}

// ---------------------------------------------------------------------------
// Kernel 2: per-batch stable LSD radix sort, 4 passes x 8-bit digits over
// key bits [16,48) of the packed uint64. One 1024-thread block per batch.
// Stability: within-wave rank via ballot digit-match (lane order == memory
// order because wave w owns the contiguous chunk [w*3072,(w+1)*3072) and
// iterates it 64 lanes at a time).
// ---------------------------------------------------------------------------
__global__ __launch_bounds__(1024) void sort_kernel(uint64_t* __restrict__ bufA,
                                                    uint64_t* __restrict__ bufB) {
    __shared__ uint32_t lds_off[256 * WAVES];   // hist -> scanned offsets
    __shared__ uint32_t lds_ws[WAVES];

    const int seg  = blockIdx.x;
    const int tid  = threadIdx.x;
    const int lane = tid & 63;
    const int w    = tid >> 6;

    uint64_t* in  = bufA + (size_t)seg * Pp;
    uint64_t* out = bufB + (size_t)seg * Pp;

    const int base_w = w * 3072;   // 3072 = 48 iters * 64 lanes per wave

    for (int pass = 0; pass < 4; ++pass) {
        const int shift = 16 + 8 * pass;

        // zero histogram
        for (int i = tid; i < 256 * WAVES; i += 1024) lds_off[i] = 0;
        __syncthreads();

        // ---- phase A: per-wave histograms ----
        for (int i = 0; i < 48; ++i) {
            uint64_t v = in[base_w + i * 64 + lane];
            uint32_t d = (uint32_t)(v >> shift) & 255u;
            atomicAdd(&lds_off[d * WAVES + w], 1u);
        }
        __syncthreads();

        // ---- scan: exclusive prefix over 4096 entries in (digit,wave) order
        uint32_t v0 = lds_off[tid * 4 + 0];
        uint32_t v1 = lds_off[tid * 4 + 1];
        uint32_t v2 = lds_off[tid * 4 + 2];
        uint32_t v3 = lds_off[tid * 4 + 3];
        uint32_t sum4 = v0 + v1 + v2 + v3;
        uint32_t s = sum4;
        for (int off = 1; off < 64; off <<= 1) {
            uint32_t n = __shfl_up(s, off);
            if (lane >= off) s += n;
        }
        if (lane == 63) lds_ws[w] = s;
        __syncthreads();
        if (tid == 0) {
            uint32_t run = 0;
            for (int i = 0; i < WAVES; ++i) { uint32_t t = lds_ws[i]; lds_ws[i] = run; run += t; }
        }
        __syncthreads();
        uint32_t excl = s - sum4 + lds_ws[w];
        lds_off[tid * 4 + 0] = excl;
        lds_off[tid * 4 + 1] = excl + v0;
        lds_off[tid * 4 + 2] = excl + v0 + v1;
        lds_off[tid * 4 + 3] = excl + v0 + v1 + v2;
        __syncthreads();

        // ---- phase B: stable scatter ----
        // volatile: slot [d][w] is read by all lanes of wave w and updated by
        // the leader lane each iteration; wave-lockstep makes this safe but
        // the compiler must not cache it in a register.
        volatile uint32_t* vOff = lds_off;
        for (int i = 0; i < 48; ++i) {
            uint64_t v = in[base_w + i * 64 + lane];
            uint32_t d = (uint32_t)(v >> shift) & 255u;
            uint64_t m = ~0ull;
            #pragma unroll
            for (int bit = 0; bit < 8; ++bit) {
                uint64_t bl = __ballot((d >> bit) & 1u);
                m &= ((d >> bit) & 1u) ? bl : ~bl;
            }
            uint32_t before = (uint32_t)__popcll(m & ((1ull << lane) - 1ull));
            uint32_t base   = vOff[d * WAVES + w];
            out[base + before] = v;
            int leader = __ffsll((unsigned long long)m) - 1;
            if (lane == leader) vOff[d * WAVES + w] = base + (uint32_t)__popcll(m);
        }
        __syncthreads();

        uint64_t* tmp = in; in = out; out = tmp;   // after 4 swaps: result in bufA
    }
}

// ---------------------------------------------------------------------------
// Kernel 3: emit output. First K rows: coords gathered by sorted index;
// remaining rows: extra_random copied straight through.
// ---------------------------------------------------------------------------
__global__ void output_kernel(const uint64_t* __restrict__ sorted,
                              const float2* __restrict__ coords,
                              const float2* __restrict__ extra,
                              float2* __restrict__ out) {
    int gid = blockIdx.x * blockDim.x + threadIdx.x;   // [0, B*P)
    int b = gid / Pp;
    int j = gid - b * Pp;
    float2 r;
    if (j < Kk) {
        uint32_t p = (uint32_t)sorted[(size_t)b * Pp + j] & 0xffffu;
        r = coords[b * Pp + p];
    } else {
        r = extra[b * NR + (j - Kk)];
    }
    out[gid] = r;
}

extern "C" void kernel_launch(void* const* d_in, const int* in_sizes, int n_in,
                              void* d_out, int out_size, void* d_ws, size_t ws_size,
                              hipStream_t stream) {
    const float*  logits = (const float*)d_in[0];   // (B,H,W,C) fp32
    const float2* coords = (const float2*)d_in[1];  // (B,P,2)  fp32
    const float2* extra  = (const float2*)d_in[2];  // (B,NR,2) fp32
    float2* out = (float2*)d_out;

    uint64_t* buf0 = (uint64_t*)d_ws;               // B*P*8 = 25.2 MB
    uint64_t* buf1 = buf0 + (size_t)Bb * Pp;        // ping-pong partner

    const int total = Bb * Pp;                      // 3,145,728
    sample_key_kernel<<<total / 256, 256, 0, stream>>>(logits, coords, buf0);
    sort_kernel<<<Bb, 1024, 0, stream>>>(buf0, buf1);
    output_kernel<<<total / 256, 256, 0, stream>>>(buf0, coords, extra, out);
}

// Round 2
// 451.176 us; speedup vs baseline: 1.1836x; 1.1836x over previous
//
#include <hip/hip_runtime.h>
#include <stdint.h>

#define Bb 64
#define Hh 128
#define Ww 128
#define Cc 21
#define Pp 49152          // NUM_SAMPLED
#define Kk 36864          // NUM_UNCERTAIN
#define NR 12288          // NUM_RANDOM

#define BINS 2048         // 11-bit digits
#define TILE 4096         // elements per sort tile
#define TILES 12          // Pp / TILE
#define NBLK (Bb * TILES) // 768 hist/scatter blocks

typedef uint32_t u32;
typedef uint64_t u64;

// ---------------------------------------------------------------------------
// Kernel 0: compact channel-0 plane: planes[b][h][w] = logits[b][h][w][0].
// Turns the sample gather's per-batch hot set from 1.38 MB into 64 KB.
// ---------------------------------------------------------------------------
__global__ __launch_bounds__(256) void extract_kernel(const float* __restrict__ logits,
                                                      float* __restrict__ planes) {
    int gid = blockIdx.x * blockDim.x + threadIdx.x;   // [0, B*H*W)
    planes[gid] = logits[(size_t)gid * Cc];
}

// ---------------------------------------------------------------------------
// Kernel 1: bilinear-sample channel 0, build sortable key, and produce the
// pass-0 per-tile histogram (digit counts are computed in write order, and
// block (s,t) covers exactly sort tile t of segment s).
// key = fp32 bits of |interp| (order-isomorphic for non-negative floats);
// packed element = (key << 16) | point_index. fp contract OFF: the sort
// permutation feeds the output directly, so bit-exact numpy arithmetic is
// required (a single rank flip = O(1) absmax error).
// ---------------------------------------------------------------------------
__global__ __launch_bounds__(256) void sample_key_kernel(const float* __restrict__ planes,
                                                         const float2* __restrict__ coords,
                                                         u64* __restrict__ keys,
                                                         u32* __restrict__ hist) {
#pragma clang fp contract(off)
    __shared__ u32 h[BINS];
    const int tid = threadIdx.x;
    const int blk = blockIdx.x;
    const int s = blk / TILES;
    const int t = blk - s * TILES;
    for (int i = tid; i < BINS; i += 256) h[i] = 0;
    __syncthreads();

    const float* plane = planes + s * (Hh * Ww);
    #pragma unroll 4
    for (int i = 0; i < 16; ++i) {
        int idx = t * TILE + i * 256 + tid;            // point index within segment
        int gid = s * Pp + idx;
        float2 c = coords[gid];
        float xf = c.x * 127.0f;                       // coords[...,0] -> H axis
        float yf = c.y * 127.0f;                       // coords[...,1] -> W axis
        float x0 = floorf(xf), x1 = ceilf(xf);
        float y0 = floorf(yf), y1 = ceilf(yf);
        float mux = xf - x0;
        float muy = yf - y0;
        int x0i = (int)x0, x1i = (int)x1, y0i = (int)y0, y1i = (int)y1;
        float p1 = plane[x0i * Ww + y0i];
        float p2 = plane[x1i * Ww + y0i];
        float p3 = plane[x0i * Ww + y1i];
        float p4 = plane[x1i * Ww + y1i];
        float p12 = p1 * (1.0f - mux) + p2 * mux;
        float p34 = p3 * (1.0f - mux) + p4 * mux;
        float r   = p12 * (1.0f - muy) + p34 * muy;
        u32 kb = __float_as_uint(r) & 0x7fffffffu;     // |r| bits
        keys[gid] = ((u64)kb << 16) | (u32)idx;
        atomicAdd(&h[kb & (BINS - 1)], 1u);            // pass-0 digit (uniform mantissa bits)
    }
    __syncthreads();
    for (int j = 0; j < 8; ++j) {
        int d = tid * 8 + j;
        hist[((size_t)s * BINS + d) * TILES + t] = h[d];
    }
}

// ---------------------------------------------------------------------------
// Kernel 2 (passes 1,2): per-tile histogram of the current buffer.
// Ballot-aggregated (leader-only atomics) — the final pass's digit is the
// exponent byte and is heavily skewed; naive atomics would serialize 64-way.
// ---------------------------------------------------------------------------
__global__ __launch_bounds__(256) void hist_kernel(const u64* __restrict__ in,
                                                   u32* __restrict__ hist, int shift) {
    __shared__ u32 h[BINS];
    const int tid = threadIdx.x;
    const int lane = tid & 63;
    const int blk = blockIdx.x;
    const int s = blk / TILES;
    const int t = blk - s * TILES;
    for (int i = tid; i < BINS; i += 256) h[i] = 0;
    __syncthreads();
    const u64* src = in + (size_t)s * Pp + t * TILE;
    for (int i = 0; i < 16; ++i) {
        u64 v = src[i * 256 + tid];
        u32 d = (u32)(v >> shift) & (BINS - 1);
        u64 m = ~0ull;
        #pragma unroll
        for (int bit = 0; bit < 11; ++bit) {
            u64 bl = __ballot((d >> bit) & 1u);
            m &= ((d >> bit) & 1u) ? bl : ~bl;
        }
        if (lane == __ffsll((unsigned long long)m) - 1)
            atomicAdd(&h[d], (u32)__popcll(m));
    }
    __syncthreads();
    for (int j = 0; j < 8; ++j) {
        int d = tid * 8 + j;
        hist[((size_t)s * BINS + d) * TILES + t] = h[d];
    }
}

// ---------------------------------------------------------------------------
// Kernel 3: per-segment exclusive scan, in place: hist[s][d][t] (counts) ->
// off[s][d][t] = sum_{d'<d, all t'} + sum_{t'<t, same d}. One 1024-thread
// block per segment; thread owns digits 2*tid, 2*tid+1 (digit order == thread
// order, required for the scan to match stable-LSD semantics).
// ---------------------------------------------------------------------------
__global__ __launch_bounds__(1024) void scan_kernel(u32* __restrict__ hist) {
    __shared__ u32 wsum[16];
    const int s = blockIdx.x;
    const int tid = threadIdx.x;
    const int lane = tid & 63;
    const int w = tid >> 6;
    u32* base = hist + (size_t)s * BINS * TILES;
    const int d0 = tid * 2, d1 = tid * 2 + 1;

    u32 c0[TILES], c1[TILES];
    u32 t0 = 0, t1 = 0;
    for (int t = 0; t < TILES; ++t) { c0[t] = base[d0 * TILES + t]; t0 += c0[t]; }
    for (int t = 0; t < TILES; ++t) { c1[t] = base[d1 * TILES + t]; t1 += c1[t]; }
    u32 ts = t0 + t1;

    // inclusive wave scan over thread sums
    u32 sc = ts;
    for (int off = 1; off < 64; off <<= 1) {
        u32 n = __shfl_up(sc, off);
        if (lane >= off) sc += n;
    }
    if (lane == 63) wsum[w] = sc;
    __syncthreads();
    if (tid == 0) {
        u32 run = 0;
        for (int i = 0; i < 16; ++i) { u32 v = wsum[i]; wsum[i] = run; run += v; }
    }
    __syncthreads();
    u32 excl = sc - ts + wsum[w];

    u32 r = excl;
    for (int t = 0; t < TILES; ++t) { u32 v = c0[t]; base[d0 * TILES + t] = r; r += v; }
    r = excl + t0;
    for (int t = 0; t < TILES; ++t) { u32 v = c1[t]; base[d1 * TILES + t] = r; r += v; }
}

// ---------------------------------------------------------------------------
// Kernel 4: stable scatter. Block (s,t) holds its 4096-element tile in
// registers (16 u64/thread), builds per-(digit,wave) bases from the global
// offsets + cross-wave wave-histogram scan, then ballot-ranks each group of
// 64 consecutive elements. Memory order == (wave chunk, iteration, lane)
// order, so ranks are stable.
// ---------------------------------------------------------------------------
__global__ __launch_bounds__(256) void scatter_kernel(const u64* __restrict__ in,
                                                      u64* __restrict__ out,
                                                      const u32* __restrict__ off,
                                                      int shift) {
    __shared__ u32 h[BINS * 4];                        // [digit][wave]
    const int tid = threadIdx.x;
    const int lane = tid & 63;
    const int w = tid >> 6;
    const int blk = blockIdx.x;
    const int s = blk / TILES;
    const int t = blk - s * TILES;
    const u64* src = in + (size_t)s * Pp + t * TILE;
    u64* dst = out + (size_t)s * Pp;

    for (int i = tid; i < BINS * 4; i += 256) h[i] = 0;

    u64 v[16];
    #pragma unroll
    for (int i = 0; i < 16; ++i) v[i] = src[w * 1024 + i * 64 + lane];
    __syncthreads();

    // phase A: per-wave histogram (ballot-aggregated, leader-only atomic)
    #pragma unroll 2
    for (int i = 0; i < 16; ++i) {
        u32 d = (u32)(v[i] >> shift) & (BINS - 1);
        u64 m = ~0ull;
        #pragma unroll
        for (int bit = 0; bit < 11; ++bit) {
            u64 bl = __ballot((d >> bit) & 1u);
            m &= ((d >> bit) & 1u) ? bl : ~bl;
        }
        if (lane == __ffsll((unsigned long long)m) - 1)
            atomicAdd(&h[d * 4 + w], (u32)__popcll(m));
    }
    __syncthreads();

    // per-(digit,wave) scatter bases: global offset + cross-wave exclusive scan.
    // Each thread owns 8 digits; reads/writes only its own slots -> no race.
    for (int j = 0; j < 8; ++j) {
        int d = tid * 8 + j;
        u32 g = off[((size_t)s * BINS + d) * TILES + t];
        u32 h0 = h[d * 4 + 0], h1 = h[d * 4 + 1], h2 = h[d * 4 + 2];
        h[d * 4 + 0] = g;
        h[d * 4 + 1] = g + h0;
        h[d * 4 + 2] = g + h0 + h1;
        h[d * 4 + 3] = g + h0 + h1 + h2;
    }
    __syncthreads();

    // phase B: stable ballot-ranked scatter. volatile: leader updates the
    // running offset each iteration; wave lockstep makes read-then-update safe.
    volatile u32* vOff = h;
    for (int i = 0; i < 16; ++i) {
        u32 d = (u32)(v[i] >> shift) & (BINS - 1);
        u64 m = ~0ull;
        #pragma unroll
        for (int bit = 0; bit < 11; ++bit) {
            u64 bl = __ballot((d >> bit) & 1u);
            m &= ((d >> bit) & 1u) ? bl : ~bl;
        }
        u32 before = (u32)__popcll(m & ((1ull << lane) - 1ull));
        u32 base = vOff[d * 4 + w];
        dst[base + before] = v[i];
        if (lane == __ffsll((unsigned long long)m) - 1)
            vOff[d * 4 + w] = base + (u32)__popcll(m);
    }
}

// ---------------------------------------------------------------------------
// Kernel 5: emit output. First K rows: coords gathered by sorted index
// (gather stays within one batch's 384 KB slice -> L2); rest: extra_random.
// Fully overwrites d_out (whose head doubled as histogram scratch).
// ---------------------------------------------------------------------------
__global__ __launch_bounds__(256) void output_kernel(const u64* __restrict__ sorted,
                                                     const float2* __restrict__ coords,
                                                     const float2* __restrict__ extra,
                                                     float2* __restrict__ out) {
    int gid = blockIdx.x * blockDim.x + threadIdx.x;   // [0, B*P)
    int b = gid / Pp;
    int j = gid - b * Pp;
    float2 r;
    if (j < Kk) {
        u32 p = (u32)sorted[(size_t)b * Pp + j] & 0xffffu;
        r = coords[b * Pp + p];
    } else {
        r = extra[b * NR + (j - Kk)];
    }
    out[gid] = r;
}

extern "C" void kernel_launch(void* const* d_in, const int* in_sizes, int n_in,
                              void* d_out, int out_size, void* d_ws, size_t ws_size,
                              hipStream_t stream) {
    const float*  logits = (const float*)d_in[0];   // (B,H,W,C) fp32
    const float2* coords = (const float2*)d_in[1];  // (B,P,2)  fp32
    const float2* extra  = (const float2*)d_in[2];  // (B,NR,2) fp32
    float2* out = (float2*)d_out;

    u64* buf0 = (u64*)d_ws;                          // 25.2 MB
    u64* buf1 = buf0 + (size_t)Bb * Pp;              // 25.2 MB (ping-pong)
    float* planes = (float*)buf1;                    // 4 MB, dead before pass-0 scatter writes buf1
    u32* hist = (u32*)d_out;                         // 6.3 MB scratch in d_out; dead before output_kernel

    const int total = Bb * Pp;

    extract_kernel<<<(Bb * Hh * Ww) / 256, 256, 0, stream>>>(logits, planes);
    sample_key_kernel<<<NBLK, 256, 0, stream>>>(planes, coords, buf0, hist);

    // pass 0: digit bits [16,27)  (buf0 -> buf1)
    scan_kernel<<<Bb, 1024, 0, stream>>>(hist);
    scatter_kernel<<<NBLK, 256, 0, stream>>>(buf0, buf1, hist, 16);
    // pass 1: digit bits [27,38)  (buf1 -> buf0)
    hist_kernel<<<NBLK, 256, 0, stream>>>(buf1, hist, 27);
    scan_kernel<<<Bb, 1024, 0, stream>>>(hist);
    scatter_kernel<<<NBLK, 256, 0, stream>>>(buf1, buf0, hist, 27);
    // pass 2: digit bits [38,47)  (buf0 -> buf1)
    hist_kernel<<<NBLK, 256, 0, stream>>>(buf0, hist, 38);
    scan_kernel<<<Bb, 1024, 0, stream>>>(hist);
    scatter_kernel<<<NBLK, 256, 0, stream>>>(buf0, buf1, hist, 38);

    output_kernel<<<total / 256, 256, 0, stream>>>(buf1, coords, extra, out);
}

// Round 3
// 399.034 us; speedup vs baseline: 1.3382x; 1.1307x over previous
//
#include <hip/hip_runtime.h>
#include <stdint.h>

#define Bb 64
#define Hh 128
#define Ww 128
#define Cc 21
#define Pp 49152          // NUM_SAMPLED
#define Kk 36864          // NUM_UNCERTAIN
#define NR 12288          // NUM_RANDOM

#define BINS 2048         // 11-bit digits; pass shifts 16/27/38 (bits 47,48 are 0)
#define TILE 4096         // elements per sort tile
#define TILES 12          // Pp / TILE
#define NBLK (Bb * TILES) // 768 hist/scatter blocks

typedef uint32_t u32;
typedef uint64_t u64;
typedef unsigned short u16;

// 11-bit ballot digit-match: mask of lanes in this wave holding digit d.
__device__ __forceinline__ u64 match11(u32 d) {
    u64 m = ~0ull;
    #pragma unroll
    for (int bit = 0; bit < 11; ++bit) {
        u64 bl = __ballot((d >> bit) & 1u);
        m &= ((d >> bit) & 1u) ? bl : ~bl;
    }
    return m;
}

// ---------------------------------------------------------------------------
// Kernel 0: compact channel-0 plane: planes[b][h][w] = logits[b][h][w][0].
// ---------------------------------------------------------------------------
__global__ __launch_bounds__(256) void extract_kernel(const float* __restrict__ logits,
                                                      float* __restrict__ planes) {
    int gid = blockIdx.x * blockDim.x + threadIdx.x;   // [0, B*H*W)
    planes[gid] = logits[(size_t)gid * Cc];
}

// ---------------------------------------------------------------------------
// Kernel 1: bilinear sample with the 64 KB plane staged in LDS (taps become
// ds_read instead of 64-divergent-line VMEM gathers), build sortable key,
// and fused pass-0 per-tile histogram.
// key = fp32 bits of |interp| (order-isomorphic for non-negative floats);
// packed element = (key << 16) | point_index. fp contract OFF: the sort
// permutation feeds the output directly — bit-exact numpy arithmetic needed.
// ---------------------------------------------------------------------------
__global__ __launch_bounds__(256) void sample_key_kernel(const float* __restrict__ planes,
                                                         const float2* __restrict__ coords,
                                                         u64* __restrict__ keys,
                                                         u32* __restrict__ hist) {
#pragma clang fp contract(off)
    __shared__ float pl[Hh * Ww];      // 64 KB
    __shared__ u32 h[BINS];            // 8 KB
    const int tid = threadIdx.x;
    const int blk = blockIdx.x;
    const int s = blk / TILES;
    const int t = blk - s * TILES;

    for (int i = tid; i < BINS; i += 256) h[i] = 0;
    const float4* p4 = (const float4*)(planes + s * (Hh * Ww));
    float4* l4 = (float4*)pl;
    #pragma unroll
    for (int i = 0; i < 16; ++i) l4[i * 256 + tid] = p4[i * 256 + tid];
    __syncthreads();

    #pragma unroll 4
    for (int i = 0; i < 16; ++i) {
        int idx = t * TILE + i * 256 + tid;            // point index within segment
        int gid = s * Pp + idx;
        float2 c = coords[gid];
        float xf = c.x * 127.0f;                       // coords[...,0] -> H axis
        float yf = c.y * 127.0f;                       // coords[...,1] -> W axis
        float x0 = floorf(xf), x1 = ceilf(xf);
        float y0 = floorf(yf), y1 = ceilf(yf);
        float mux = xf - x0;
        float muy = yf - y0;
        int x0i = (int)x0, x1i = (int)x1, y0i = (int)y0, y1i = (int)y1;
        float p1 = pl[x0i * Ww + y0i];
        float p2 = pl[x1i * Ww + y0i];
        float p3 = pl[x0i * Ww + y1i];
        float p4v = pl[x1i * Ww + y1i];
        float p12 = p1 * (1.0f - mux) + p2 * mux;
        float p34 = p3 * (1.0f - mux) + p4v * mux;
        float r   = p12 * (1.0f - muy) + p34 * muy;
        u32 kb = __float_as_uint(r) & 0x7fffffffu;     // |r| bits
        keys[gid] = ((u64)kb << 16) | (u32)idx;
        atomicAdd(&h[kb & (BINS - 1)], 1u);            // pass-0 digit (uniform)
    }
    __syncthreads();
    for (int j = 0; j < 8; ++j) {
        int d = tid * 8 + j;
        hist[((size_t)s * BINS + d) * TILES + t] = h[d];
    }
}

// ---------------------------------------------------------------------------
// Kernel 2 (passes 1,2): per-tile histogram, ballot-aggregated LDS atomics
// (final pass digit = exponent bits, heavily skewed).
// ---------------------------------------------------------------------------
__global__ __launch_bounds__(256) void hist_kernel(const u64* __restrict__ in,
                                                   u32* __restrict__ hist, int shift) {
    __shared__ u32 h[BINS];
    const int tid = threadIdx.x;
    const int lane = tid & 63;
    const int blk = blockIdx.x;
    const int s = blk / TILES;
    const int t = blk - s * TILES;
    for (int i = tid; i < BINS; i += 256) h[i] = 0;
    __syncthreads();
    const u64* src = in + (size_t)s * Pp + t * TILE;
    for (int i = 0; i < 16; ++i) {
        u64 v = src[i * 256 + tid];
        u32 d = (u32)(v >> shift) & (BINS - 1);
        u64 m = match11(d);
        if (lane == __ffsll((unsigned long long)m) - 1)
            atomicAdd(&h[d], (u32)__popcll(m));
    }
    __syncthreads();
    for (int j = 0; j < 8; ++j) {
        int d = tid * 8 + j;
        hist[((size_t)s * BINS + d) * TILES + t] = h[d];
    }
}

// ---------------------------------------------------------------------------
// Kernel 3: per-segment exclusive scan of hist[s][d][t], in place.
// ---------------------------------------------------------------------------
__global__ __launch_bounds__(1024) void scan_kernel(u32* __restrict__ hist) {
    __shared__ u32 wsum[16];
    const int s = blockIdx.x;
    const int tid = threadIdx.x;
    const int lane = tid & 63;
    const int w = tid >> 6;
    u32* base = hist + (size_t)s * BINS * TILES;
    const int d0 = tid * 2, d1 = tid * 2 + 1;

    u32 c0[TILES], c1[TILES];
    u32 t0 = 0, t1 = 0;
    for (int t = 0; t < TILES; ++t) { c0[t] = base[d0 * TILES + t]; t0 += c0[t]; }
    for (int t = 0; t < TILES; ++t) { c1[t] = base[d1 * TILES + t]; t1 += c1[t]; }
    u32 ts = t0 + t1;

    u32 sc = ts;
    for (int off = 1; off < 64; off <<= 1) {
        u32 n = __shfl_up(sc, off);
        if (lane >= off) sc += n;
    }
    if (lane == 63) wsum[w] = sc;
    __syncthreads();
    if (tid == 0) {
        u32 run = 0;
        for (int i = 0; i < 16; ++i) { u32 v = wsum[i]; wsum[i] = run; run += v; }
    }
    __syncthreads();
    u32 excl = sc - ts + wsum[w];

    u32 r = excl;
    for (int t = 0; t < TILES; ++t) { u32 v = c0[t]; base[d0 * TILES + t] = r; r += v; }
    r = excl + t0;
    for (int t = 0; t < TILES; ++t) { u32 v = c1[t]; base[d1 * TILES + t] = r; r += v; }
}

// ---------------------------------------------------------------------------
// Kernel 4: stable scatter with LDS local reorder. The tile is ballot-ranked
// into LDS in locally-sorted order, then written out LINEARLY: consecutive
// local positions within a digit run map to consecutive global addresses ->
// coalesced stores (vs 1 line per element before).
// gaddr = pos + delta[d], delta[d] = off_global[d] - local_start[d] (mod 2^16
// is exact since all segment offsets < 49152 < 2^16).
// Final pass: emit out[s][g] = coords[s][idx] directly for g < K (skips the
// last key write AND the whole output kernel).
// ---------------------------------------------------------------------------
__global__ __launch_bounds__(256) void scatter_kernel(const u64* __restrict__ in,
                                                      u64* __restrict__ out_keys,
                                                      const u32* __restrict__ off,
                                                      int shift, int final_pass,
                                                      const float2* __restrict__ coords,
                                                      float2* __restrict__ out) {
    __shared__ u64 el[TILE];           // 32 KB
    __shared__ u16 wh[BINS * 4];       // 16 KB  [digit][wave] counts -> local bases
    __shared__ u16 dl[BINS];           // 4 KB   delta[d] (mod 2^16)
    __shared__ u32 aux[4];
    const int tid = threadIdx.x;
    const int lane = tid & 63;
    const int w = tid >> 6;
    const int blk = blockIdx.x;
    const int s = blk / TILES;
    const int t = blk - s * TILES;
    const u64* src = in + (size_t)s * Pp + t * TILE;

    for (int i = tid; i < BINS * 4; i += 256) wh[i] = 0;
    u64 v[16];
    #pragma unroll
    for (int i = 0; i < 16; ++i) v[i] = src[w * 1024 + i * 64 + lane];
    __syncthreads();

    // phase A: per-wave digit histogram (leader-only LDS RMW; wave-lockstep safe)
    volatile u16* vwh = wh;
    for (int i = 0; i < 16; ++i) {
        u32 d = (u32)(v[i] >> shift) & (BINS - 1);
        u64 m = match11(d);
        if (lane == __ffsll((unsigned long long)m) - 1) {
            u32 idx = d * 4 + w;
            vwh[idx] = (u16)(vwh[idx] + (u32)__popcll(m));
        }
    }
    __syncthreads();

    // scan: thread owns 8 digits; local exclusive digit bases + per-wave bases.
    const int d0 = tid * 8;
    u32 dtot[8];
    u32 t8 = 0;
    #pragma unroll
    for (int j = 0; j < 8; ++j) {
        int d = d0 + j;
        u32 c = (u32)wh[d * 4 + 0] + wh[d * 4 + 1] + wh[d * 4 + 2] + wh[d * 4 + 3];
        dtot[j] = c;
        t8 += c;
    }
    u32 sc = t8;
    for (int o = 1; o < 64; o <<= 1) {
        u32 n = __shfl_up(sc, o);
        if (lane >= o) sc += n;
    }
    if (lane == 63) aux[w] = sc;
    __syncthreads();
    if (tid == 0) {
        u32 run = 0;
        for (int i = 0; i < 4; ++i) { u32 x = aux[i]; aux[i] = run; run += x; }
    }
    __syncthreads();
    u32 run = sc - t8 + aux[w];       // exclusive base for this thread's digits
    #pragma unroll
    for (int j = 0; j < 8; ++j) {
        int d = d0 + j;
        u32 ls = run;                 // local_start[d]
        u32 g = off[((size_t)s * BINS + d) * TILES + t];
        dl[d] = (u16)(g - ls);
        u32 c0 = wh[d * 4 + 0], c1 = wh[d * 4 + 1], c2 = wh[d * 4 + 2];
        wh[d * 4 + 0] = (u16)ls;
        wh[d * 4 + 1] = (u16)(ls + c0);
        wh[d * 4 + 2] = (u16)(ls + c0 + c1);
        wh[d * 4 + 3] = (u16)(ls + c0 + c1 + c2);
        run += dtot[j];
    }
    __syncthreads();

    // phase B: stable ballot-ranked scatter into LDS (local sorted order)
    for (int i = 0; i < 16; ++i) {
        u32 d = (u32)(v[i] >> shift) & (BINS - 1);
        u64 m = match11(d);
        u32 before = (u32)__popcll(m & ((1ull << lane) - 1ull));
        u32 base = vwh[d * 4 + w];
        el[base + before] = v[i];
        if (lane == __ffsll((unsigned long long)m) - 1)
            vwh[d * 4 + w] = (u16)(base + (u32)__popcll(m));
    }
    __syncthreads();

    // phase C: linear read-back, coalesced global write
    if (!final_pass) {
        u64* dst = out_keys + (size_t)s * Pp;
        for (int i = 0; i < 16; ++i) {
            int pos = i * 256 + tid;
            u64 e = el[pos];
            u32 d = (u32)(e >> shift) & (BINS - 1);
            u32 g = (u32)(u16)(pos + dl[d]);
            dst[g] = e;
        }
    } else {
        const float2* cseg = coords + (size_t)s * Pp;
        float2* oseg = out + (size_t)s * Pp;
        for (int i = 0; i < 16; ++i) {
            int pos = i * 256 + tid;
            u64 e = el[pos];
            u32 d = (u32)(e >> shift) & (BINS - 1);
            u32 g = (u32)(u16)(pos + dl[d]);
            if (g < Kk) {
                u32 idx = (u32)e & 0xffffu;
                oseg[g] = cseg[idx];
            }
        }
    }
}

// ---------------------------------------------------------------------------
// Kernel 5: copy extra_random into rows [K, P) of each segment.
// ---------------------------------------------------------------------------
__global__ __launch_bounds__(256) void extra_copy_kernel(const float2* __restrict__ extra,
                                                         float2* __restrict__ out) {
    int gid = blockIdx.x * blockDim.x + threadIdx.x;   // [0, B*NR)
    int b = gid / NR;
    int j = gid - b * NR;
    out[(size_t)b * Pp + Kk + j] = extra[gid];
}

extern "C" void kernel_launch(void* const* d_in, const int* in_sizes, int n_in,
                              void* d_out, int out_size, void* d_ws, size_t ws_size,
                              hipStream_t stream) {
    const float*  logits = (const float*)d_in[0];   // (B,H,W,C) fp32
    const float2* coords = (const float2*)d_in[1];  // (B,P,2)  fp32
    const float2* extra  = (const float2*)d_in[2];  // (B,NR,2) fp32
    float2* out = (float2*)d_out;

    u64* buf0 = (u64*)d_ws;                          // 25.2 MB
    u64* buf1 = buf0 + (size_t)Bb * Pp;              // 25.2 MB (ping-pong)
    float* planes = (float*)buf1;                    // 4 MB; dead before pass-0 scatter writes buf1
    u32* histA = (u32*)d_out;                        // 6.3 MB scratch (passes 0,1); d_out untouched until final pass
    u32* histB = (u32*)buf1;                         // final-pass hist lives in buf1 (dead then) — final scatter writes d_out

    extract_kernel<<<(Bb * Hh * Ww) / 256, 256, 0, stream>>>(logits, planes);
    sample_key_kernel<<<NBLK, 256, 0, stream>>>(planes, coords, buf0, histA);

    // pass 0: bits [16,27)  buf0 -> buf1
    scan_kernel<<<Bb, 1024, 0, stream>>>(histA);
    scatter_kernel<<<NBLK, 256, 0, stream>>>(buf0, buf1, histA, 16, 0, nullptr, nullptr);
    // pass 1: bits [27,38)  buf1 -> buf0
    hist_kernel<<<NBLK, 256, 0, stream>>>(buf1, histA, 27);
    scan_kernel<<<Bb, 1024, 0, stream>>>(histA);
    scatter_kernel<<<NBLK, 256, 0, stream>>>(buf1, buf0, histA, 27, 0, nullptr, nullptr);
    // pass 2: bits [38,47)  buf0 -> out (fused gather+emit)
    hist_kernel<<<NBLK, 256, 0, stream>>>(buf0, histB, 38);
    scan_kernel<<<Bb, 1024, 0, stream>>>(histB);
    scatter_kernel<<<NBLK, 256, 0, stream>>>(buf0, nullptr, histB, 38, 1, coords, out);

    extra_copy_kernel<<<(Bb * NR) / 256, 256, 0, stream>>>(extra, out);
}